// Round 7
// baseline (660.376 us; speedup 1.0000x reference)
//
#include <hip/hip_runtime.h>
#include <cstdint>
#include <cstddef>

// GTM forward: out[0] = -ll, out[1..] = R^T [N=131072][K=360]
//   E'_k(n) = b*(Y_k . t_n - 0.5*||Y_k||^2)   (||t||^2 shift cancels)
//   R[:,n] = softmax_k(E'), ll_n = 256*log(b/2pi) + log(sum exp(E'-max)) - log 360
//
// R6 -> R7: all fused variants pinned at 228-246 us because the fused 384-row
// accumulator (96 AGPR, unified RF) register-locks occupancy to ~2 waves/SIMD
// in ONE lockstep barrier domain. Split design:
//   k_gemm: 128x64 tiles, acc=32 AGPR -> 16 waves/CU (4 blocks x 4 waves),
//           writes E transposed INTO d_out (same addresses R^T will occupy).
//   k_soft: row-streaming softmax in place over out (E is L3-warm), 64-slot
//           spread atomics for sum(log s).
// GEMM is 3-pass bf16 hi/lo; A direct-from-global (L2-resident, proven R6).

#define KNODES 360
#define MRBF   145
#define DD     512
#define NTOT   131072
#define NT     64              // cols per k_gemm block
#define RT     128             // rows per k_gemm block
#define NKS    16              // K-steps of 32
#define ACHUNK 24576           // bytes per A K-chunk: 384 rows * 32 k * 2 B

#define LDS_TOT 34816          // max(B dbuf 2x8192, 4 waves x 8704 transpose)

typedef float  f32x4  __attribute__((ext_vector_type(4)));
typedef short  s16x8  __attribute__((ext_vector_type(8)));
typedef __bf16 bf16x8 __attribute__((ext_vector_type(8)));

static __device__ __forceinline__ bf16x8 as_bf(s16x8 v) { return __builtin_bit_cast(bf16x8, v); }

// round-to-nearest-even fp32 -> bf16 (data has no NaN/Inf)
static __device__ __forceinline__ unsigned short f2bf(float x) {
  unsigned u = __float_as_uint(x);
  u += 0x7FFFu + ((u >> 16) & 1u);
  return (unsigned short)(u >> 16);
}
static __device__ __forceinline__ float bf2f(unsigned short h) {
  return __uint_as_float(((unsigned)h) << 16);
}

// ---------------------------------------------------------------------------
// prep: Y = phi@W, one element per thread (360 blocks x 512 threads).
// Linear chunked layout: chunk (d>>5) | row k | (d&31). Rows 360..383 never
// written (k_gemm reads finite poison; rows masked at store).
// ---------------------------------------------------------------------------
__global__ __launch_bounds__(512) void k_prep(const float* __restrict__ W,
                                              unsigned short* __restrict__ ahi,
                                              unsigned short* __restrict__ alo,
                                              float* __restrict__ cbuf,
                                              float* __restrict__ llbuf) {
  const int k   = blockIdx.x;    // latent row 0..359
  const int tid = threadIdx.x;   // = d, 0..511

  if (k == 0 && tid < 64) llbuf[tid] = 0.0f;   // runs before k_soft (stream order)

  __shared__ float phi[MRBF];
  __shared__ float rw[8];

  if (tid < MRBF) {
    float p = 1.0f;                              // bias column (m == 144)
    if (tid < MRBF - 1) {
      const float ca = -11.0f / 12.0f + (1.0f / 6.0f) * (float)(tid / 12);
      const float cb = -11.0f / 12.0f + (1.0f / 6.0f) * (float)(tid % 12);
      const float xa = -1.0f + (2.0f / 19.0f) * (float)(k / 18);
      const float xb = -1.0f + (2.0f / 17.0f) * (float)(k % 18);
      const float dx = xa - ca, dy = xb - cb;
      p = expf(-3.0f * (dx * dx + dy * dy));     // exp(-d2/(2*sigma)), sigma=1/6
    }
    phi[tid] = p;
  }
  __syncthreads();

  float y0 = 0.0f, y1 = 0.0f, y2 = 0.0f, y3 = 0.0f;
  #pragma unroll 4
  for (int m = 0; m < 144; m += 4) {
    y0 = fmaf(phi[m],     W[(m)     * DD + tid], y0);
    y1 = fmaf(phi[m + 1], W[(m + 1) * DD + tid], y1);
    y2 = fmaf(phi[m + 2], W[(m + 2) * DD + tid], y2);
    y3 = fmaf(phi[m + 3], W[(m + 3) * DD + tid], y3);
  }
  const float y = ((y0 + y1) + (y2 + y3)) + W[144 * DD + tid];  // phi[144]=1

  const unsigned short h = f2bf(y);
  const unsigned short l = f2bf(y - bf2f(h));
  const int idx = (tid >> 5) * (ACHUNK / 2) + k * 32 + (tid & 31);
  ahi[idx] = h;
  alo[idx] = l;

  float q = y * y;
  #pragma unroll
  for (int mk = 1; mk < 64; mk <<= 1) q += __shfl_xor(q, mk);
  if ((tid & 63) == 0) rw[tid >> 6] = q;
  __syncthreads();
  if (tid == 0) {
    float s = 0.0f;
    #pragma unroll
    for (int i = 0; i < 8; ++i) s += rw[i];
    cbuf[k] = 0.5f * s;
  }
}

// ---------------------------------------------------------------------------
// gemm: block = 128 rows x 64 cols; 4 waves = 2(row-half) x 2(col-half), each
// 64x32 -> acc 4x2 f32x4 = 32 AGPR. A direct-from-global; B (t) hi/lo dbuf in
// LDS with lgkm-only raw barrier. Epilogue: E=(dot-c)*b, per-wave LDS
// transpose (no barriers), coalesced column stores into out[1+n*360+row].
// ---------------------------------------------------------------------------
__global__ __launch_bounds__(256, 4) void k_gemm(const float* __restrict__ t,
                                                 const float* __restrict__ beta,
                                                 const unsigned short* __restrict__ ahi,
                                                 const unsigned short* __restrict__ alo,
                                                 const float* __restrict__ cbuf,
                                                 float* __restrict__ out) {
  __shared__ __align__(16) char smem[LDS_TOT];
  const int tid  = threadIdx.x;
  const int lane = tid & 63;
  const int wv   = tid >> 6;     // 0..3
  const int wm2  = wv & 1;       // row-half: rows [rt*128 + wm2*64, +64)
  const int wn2  = wv >> 1;      // col-half: cols [n0 + wn2*32, +32)
  const int col  = lane & 15;
  const int kg   = lane >> 4;
  const int bid  = blockIdx.x;   // 6144 = 3 row-tiles x 2048 n-tiles
  const int rt   = bid % 3;
  const int n0   = (bid / 3) * NT;
  const float b  = beta[0];

  f32x4 acc[4][2] = {};          // row = rt*128+wm2*64+i*16+kg*4+r, col = n0+wn2*32+j*16+col

  const float* tsrc = t + (size_t)(n0 + (tid >> 2)) * DD + (tid & 3) * 8;
  const int brow  = tid >> 2;    // B tile row = n-local 0..63
  const int bbyte = ((brow * 64 + (tid & 3) * 16) ^ ((brow & 7) << 4));

  const char* aposH = (const char*)ahi + (rt * 128 + wm2 * 64 + col) * 64 + kg * 16;
  const char* aposL = (const char*)alo + (rt * 128 + wm2 * 64 + col) * 64 + kg * 16;
  const int bfbase = (((wn2 * 32 + col) * 64 + kg * 16) ^ ((col & 7) << 4));

  auto bconv = [&](int sbuf, float4 v0, float4 v1) {
    char* db = smem + sbuf * 8192;
    const float f[8] = {v0.x, v0.y, v0.z, v0.w, v1.x, v1.y, v1.z, v1.w};
    s16x8 hv, lv;
    #pragma unroll
    for (int q = 0; q < 8; ++q) {
      const unsigned short h = f2bf(f[q]);
      hv[q] = (short)h;
      lv[q] = (short)f2bf(f[q] - bf2f(h));
    }
    *(s16x8*)(db + bbyte) = hv;
    *(s16x8*)(db + 4096 + bbyte) = lv;
  };

#define STEP(KS, CUR, TU0, TU1, TP0, TP1)                                      \
  {                                                                            \
    const int ks_ = (KS);                                                      \
    if (ks_ < NKS - 2) {                                                       \
      TP0 = *(const float4*)(tsrc + (ks_ + 2) * 32);                           \
      TP1 = *(const float4*)(tsrc + (ks_ + 2) * 32 + 4);                       \
    }                                                                          \
    s16x8 Ah[4], Al[4];                                                        \
    _Pragma("unroll")                                                          \
    for (int i = 0; i < 4; ++i) {                                              \
      Ah[i] = *(const s16x8*)(aposH + ks_ * ACHUNK + i * 1024);                \
      Al[i] = *(const s16x8*)(aposL + ks_ * ACHUNK + i * 1024);                \
    }                                                                          \
    const char* Bb = smem + (CUR) * 8192;                                      \
    s16x8 Bh[2], Bl[2];                                                        \
    _Pragma("unroll")                                                          \
    for (int j = 0; j < 2; ++j) {                                              \
      Bh[j] = *(const s16x8*)(Bb + bfbase + j * 1024);                         \
      Bl[j] = *(const s16x8*)(Bb + 4096 + bfbase + j * 1024);                  \
    }                                                                          \
    if (ks_ < NKS - 1) bconv((CUR) ^ 1, TU0, TU1);                             \
    __builtin_amdgcn_s_setprio(1);                                             \
    _Pragma("unroll")                                                          \
    for (int i = 0; i < 4; ++i) {                                              \
      _Pragma("unroll")                                                        \
      for (int j = 0; j < 2; ++j) {                                            \
        acc[i][j] = __builtin_amdgcn_mfma_f32_16x16x32_bf16(as_bf(Ah[i]), as_bf(Bh[j]), acc[i][j], 0, 0, 0); \
        acc[i][j] = __builtin_amdgcn_mfma_f32_16x16x32_bf16(as_bf(Ah[i]), as_bf(Bl[j]), acc[i][j], 0, 0, 0); \
        acc[i][j] = __builtin_amdgcn_mfma_f32_16x16x32_bf16(as_bf(Al[i]), as_bf(Bh[j]), acc[i][j], 0, 0, 0); \
      }                                                                        \
    }                                                                          \
    __builtin_amdgcn_s_setprio(0);                                             \
    asm volatile("s_waitcnt lgkmcnt(0)" ::: "memory");                         \
    __builtin_amdgcn_s_barrier();                                              \
    __builtin_amdgcn_sched_barrier(0);                                         \
  }

  // prologue: B chunk 0 into buf0; t chunk 1 into regs
  {
    const float4 v0 = *(const float4*)(tsrc);
    const float4 v1 = *(const float4*)(tsrc + 4);
    bconv(0, v0, v1);
  }
  float4 ta0 = *(const float4*)(tsrc + 32);
  float4 ta1 = *(const float4*)(tsrc + 36);
  float4 tb0 = {}, tb1 = {};
  asm volatile("s_waitcnt lgkmcnt(0)" ::: "memory");
  __builtin_amdgcn_s_barrier();
  __builtin_amdgcn_sched_barrier(0);

  for (int kk = 0; kk < 8; ++kk) {
    STEP(2 * kk,     0, ta0, ta1, tb0, tb1)
    STEP(2 * kk + 1, 1, tb0, tb1, ta0, ta1)
  }
#undef STEP
  // final STEP's barrier: all waves' LDS reads done -> safe to overlay smem.

  // ---- epilogue: E = (dot - c)*b; per-wave transpose (no block barriers)
  f32x4 c4[4];
  #pragma unroll
  for (int i = 0; i < 4; ++i)
    c4[i] = *(const f32x4*)(cbuf + rt * 128 + wm2 * 64 + i * 16 + kg * 4);
  #pragma unroll
  for (int i = 0; i < 4; ++i) {
    #pragma unroll
    for (int j = 0; j < 2; ++j) acc[i][j] = (acc[i][j] - c4[i]) * b;
  }

  char* tw = smem + wv * 8704;   // [32 n][67 f32] per wave
  #pragma unroll
  for (int i = 0; i < 4; ++i) {
    #pragma unroll
    for (int j = 0; j < 2; ++j)
      *(f32x4*)(tw + (j * 16 + col) * 268 + (i * 16 + kg * 4) * 4) = acc[i][j];
  }
  asm volatile("s_waitcnt lgkmcnt(0)" ::: "memory");

  const int row = rt * 128 + wm2 * 64 + lane;
  const bool ok = row < KNODES;
  #pragma unroll 8
  for (int nn = 0; nn < 32; ++nn) {
    const float v = *(const float*)(tw + nn * 268 + lane * 4);
    if (ok) out[1 + (size_t)(n0 + wn2 * 32 + nn) * KNODES + row] = v;
  }
}

// ---------------------------------------------------------------------------
// soft: in-place row softmax over out[1 + n*360 .. +360), accumulate log s.
// 2048 blocks x 256 thr; wave handles 16 consecutive rows.
// ---------------------------------------------------------------------------
__global__ __launch_bounds__(256) void k_soft(float* __restrict__ out,
                                              float* __restrict__ llbuf) {
  const int tid  = threadIdx.x;
  const int lane = tid & 63;
  const int wv   = tid >> 6;
  __shared__ float wsum[4];

  float ll = 0.0f;
  const int nbase = (blockIdx.x * 4 + wv) * 16;
  for (int it = 0; it < 16; ++it) {
    float* row = out + 1 + (size_t)(nbase + it) * KNODES;
    float v[6];
    #pragma unroll
    for (int c = 0; c < 5; ++c) v[c] = row[c * 64 + lane];
    const bool m5 = lane < 40;                      // 360 = 5*64 + 40
    v[5] = m5 ? row[320 + lane] : -3.0e38f;

    float mx = fmaxf(fmaxf(fmaxf(v[0], v[1]), fmaxf(v[2], v[3])), fmaxf(v[4], v[5]));
    #pragma unroll
    for (int mk = 1; mk < 64; mk <<= 1) mx = fmaxf(mx, __shfl_xor(mx, mk));

    float s = 0.0f;
    #pragma unroll
    for (int c = 0; c < 6; ++c) {
      const float p = expf(v[c] - mx);              // masked lanes: exp(-huge)=0
      v[c] = p;
      s += p;
    }
    #pragma unroll
    for (int mk = 1; mk < 64; mk <<= 1) s += __shfl_xor(s, mk);

    const float inv = 1.0f / s;
    #pragma unroll
    for (int c = 0; c < 5; ++c) row[c * 64 + lane] = v[c] * inv;
    if (m5) row[320 + lane] = v[5] * inv;
    if (lane == 0) ll += logf(s);
  }
  if (lane == 0) wsum[wv] = ll;
  __syncthreads();
  if (tid == 0)
    atomicAdd(&llbuf[blockIdx.x & 63], (wsum[0] + wsum[1]) + (wsum[2] + wsum[3]));
}

// ---------------------------------------------------------------------------
__global__ void k_fin(const float* __restrict__ beta, const float* __restrict__ llbuf,
                      float* __restrict__ out) {
  const float b = beta[0];
  float s = 0.0f;
  for (int i = 0; i < 64; ++i) s += llbuf[i];
  out[0] = -(256.0f * logf(b * (1.0f / 6.283185307179586f)) - logf(360.0f)
             + s * (1.0f / 131072.0f));
}

extern "C" void kernel_launch(void* const* d_in, const int* in_sizes, int n_in,
                              void* d_out, int out_size, void* d_ws, size_t ws_size,
                              hipStream_t stream) {
  const float* t    = (const float*)d_in[0];
  const float* W    = (const float*)d_in[1];
  const float* beta = (const float*)d_in[2];
  float* out = (float*)d_out;

  // ws: A_hi[393216] | A_lo[393216] | cbuf[1536: 384 slots, 360 written] | llbuf[64 f32]
  unsigned short* ahi = (unsigned short*)d_ws;
  unsigned short* alo = (unsigned short*)((char*)d_ws + 393216);
  float* cbuf  = (float*)((char*)d_ws + 786432);
  float* llbuf = (float*)((char*)d_ws + 787968);

  hipLaunchKernelGGL(k_prep, dim3(KNODES), dim3(512), 0, stream, W, ahi, alo, cbuf, llbuf);
  hipLaunchKernelGGL(k_gemm, dim3(3 * (NTOT / NT)), dim3(256), 0, stream,
                     t, beta, ahi, alo, cbuf, out);
  hipLaunchKernelGGL(k_soft, dim3(NTOT / 64), dim3(256), 0, stream, out, llbuf);
  hipLaunchKernelGGL(k_fin, dim3(1), dim3(1), 0, stream, beta, llbuf, out);
}